// Round 1
// baseline (345.705 us; speedup 1.0000x reference)
//
#include <hip/hip_runtime.h>

#define CODE_DIM 256
#define KCODES   1024
#define NT       64     // queries per block
#define PAD      68     // row stride (floats) for [c][*] LDS tiles (16B-aligned rows)

__global__ __launch_bounds__(256) void vq_kernel(
    const float* __restrict__ z,    // [32,256,32,32]
    const float* __restrict__ w,    // [1024,256]
    float* __restrict__ out)        // code(8388608) | detached(8388608) | idx(32768) as float
{
    __shared__ float zt[64][PAD];
    __shared__ float wt[64][PAD];
    __shared__ float w2s[KCODES];
    __shared__ float redv[NT][16];
    __shared__ int   redi[NT][16];
    __shared__ int   idxb[NT];

    const int t   = threadIdx.x;
    const int tn4 = (t & 15) * 4;
    const int tk4 = (t >> 4) * 4;

    // ---- prologue: ||w_k||^2 for all k (redundant per block, avoids d_ws)
    for (int kk = t; kk < KCODES; kk += 256) {
        const float* row = w + (size_t)kk * CODE_DIM;
        float s = 0.0f;
        for (int c = 0; c < CODE_DIM; ++c) { float v = row[c]; s += v * v; }
        w2s[kk] = s;
    }

    const int n0  = blockIdx.x * NT;
    const int b   = n0 >> 10;
    const int hw0 = n0 & 1023;
    const float* zb = z + (size_t)b * CODE_DIM * 1024 + hw0;   // z[b][c=0][hw0]

    float rmin[4], z2[4];
    int   ridx[4];
    #pragma unroll
    for (int i = 0; i < 4; ++i) { rmin[i] = 3.4e38f; ridx[i] = 0; z2[i] = 0.0f; }

    for (int kt = 0; kt < 16; ++kt) {
        float acc[4][4];
        #pragma unroll
        for (int i = 0; i < 4; ++i)
            #pragma unroll
            for (int j = 0; j < 4; ++j) acc[i][j] = 0.0f;

        for (int ct = 0; ct < 4; ++ct) {
            __syncthreads();
            // stage z chunk: zt[c][n], coalesced
            #pragma unroll
            for (int r = 0; r < 4; ++r) {
                int s = t + r * 256;
                int cc = s >> 4, nseg = s & 15;
                float4 v = *reinterpret_cast<const float4*>(
                    zb + (size_t)(ct * 64 + cc) * 1024 + nseg * 4);
                *reinterpret_cast<float4*>(&zt[cc][nseg * 4]) = v;
            }
            // stage w chunk transposed: wt[c][k]
            #pragma unroll
            for (int r = 0; r < 4; ++r) {
                int kl = (t >> 4) + r * 16;
                int cl = (t & 15) * 4;
                float4 v = *reinterpret_cast<const float4*>(
                    w + (size_t)(kt * 64 + kl) * CODE_DIM + ct * 64 + cl);
                wt[cl + 0][kl] = v.x;
                wt[cl + 1][kl] = v.y;
                wt[cl + 2][kl] = v.z;
                wt[cl + 3][kl] = v.w;
            }
            __syncthreads();

            if (kt == 0) {
                #pragma unroll 4
                for (int c = 0; c < 64; ++c) {
                    float4 zv = *reinterpret_cast<const float4*>(&zt[c][tn4]);
                    float4 wv = *reinterpret_cast<const float4*>(&wt[c][tk4]);
                    float zr[4] = {zv.x, zv.y, zv.z, zv.w};
                    float wr[4] = {wv.x, wv.y, wv.z, wv.w};
                    #pragma unroll
                    for (int i = 0; i < 4; ++i) {
                        #pragma unroll
                        for (int j = 0; j < 4; ++j) acc[i][j] += zr[i] * wr[j];
                        z2[i] += zr[i] * zr[i];
                    }
                }
            } else {
                #pragma unroll 4
                for (int c = 0; c < 64; ++c) {
                    float4 zv = *reinterpret_cast<const float4*>(&zt[c][tn4]);
                    float4 wv = *reinterpret_cast<const float4*>(&wt[c][tk4]);
                    float zr[4] = {zv.x, zv.y, zv.z, zv.w};
                    float wr[4] = {wv.x, wv.y, wv.z, wv.w};
                    #pragma unroll
                    for (int i = 0; i < 4; ++i)
                        #pragma unroll
                        for (int j = 0; j < 4; ++j) acc[i][j] += zr[i] * wr[j];
                }
            }
        }

        // finalize this k-tile: dist = fl(fl(z2 - fl(2*dot)) + w2), per-thread k ascending
        #pragma unroll
        for (int j = 0; j < 4; ++j) {
            int kk = kt * 64 + tk4 + j;
            float w2v = w2s[kk];
            #pragma unroll
            for (int i = 0; i < 4; ++i) {
                float d = (z2[i] - 2.0f * acc[i][j]) + w2v;
                if (d < rmin[i]) { rmin[i] = d; ridx[i] = kk; }
            }
        }
    }

    // ---- cross-thread argmin reduce (tie-break: lowest k)
    __syncthreads();
    #pragma unroll
    for (int i = 0; i < 4; ++i) {
        redv[tn4 + i][t >> 4] = rmin[i];
        redi[tn4 + i][t >> 4] = ridx[i];
    }
    __syncthreads();
    if (t < NT) {
        float bv = redv[t][0]; int bi = redi[t][0];
        for (int q = 1; q < 16; ++q) {
            float v = redv[t][q]; int ii = redi[t][q];
            if (v < bv || (v == bv && ii < bi)) { bv = v; bi = ii; }
        }
        idxb[t] = bi;
        out[2 * 8388608 + n0 + t] = (float)bi;   // idx as float
    }
    __syncthreads();

    // ---- gather + transpose epilogue (reuse zt as gather buffer)
    float (*gbuf)[PAD] = zt;
    float* out0 = out;
    float* out1 = out + 8388608;
    const size_t obase = (size_t)b * CODE_DIM * 1024 + hw0;

    for (int ct = 0; ct < 4; ++ct) {
        __syncthreads();
        {
            int n = t & 63, seg = t >> 6;
            int kk = idxb[n];
            #pragma unroll
            for (int u = 0; u < 4; ++u) {
                int c = seg * 16 + u * 4;
                float4 v = *reinterpret_cast<const float4*>(
                    w + (size_t)kk * CODE_DIM + ct * 64 + c);
                gbuf[c + 0][n] = v.x;
                gbuf[c + 1][n] = v.y;
                gbuf[c + 2][n] = v.z;
                gbuf[c + 3][n] = v.w;
            }
        }
        __syncthreads();
        #pragma unroll
        for (int p = 0; p < 16; ++p) {
            int c = p * 4 + (t >> 6);
            int n = t & 63;
            float cv = gbuf[c][n];
            size_t off = (size_t)(ct * 64 + c) * 1024 + n;
            float zz = zb[off];
            out0[obase + off] = cv;
            out1[obase + off] = (cv - zz) + zz;   // replicate reference rounding chain
        }
    }
}

extern "C" void kernel_launch(void* const* d_in, const int* in_sizes, int n_in,
                              void* d_out, int out_size, void* d_ws, size_t ws_size,
                              hipStream_t stream) {
    const float* z = (const float*)d_in[0];
    const float* w = (const float*)d_in[1];
    float* out = (float*)d_out;
    vq_kernel<<<512, 256, 0, stream>>>(z, w, out);
}